// Round 5
// baseline (461.756 us; speedup 1.0000x reference)
//
#include <hip/hip_runtime.h>
#include <hip/hip_bf16.h>
#include <stdint.h>
#include <string.h>

using bf16 = __hip_bfloat16;
typedef __attribute__((ext_vector_type(8))) short bf16x8;   // 8 bf16 (4 VGPRs) MFMA A/B frag
typedef __attribute__((ext_vector_type(4))) float f32x4;    // MFMA C/D frag

#define DEV static __device__ __forceinline__

DEV bf16 tobf(float f) { return __float2bfloat16(f); }
DEV float tof(bf16 h) { return __bfloat162float(h); }

// async global->LDS, 16B per lane. LDS dest semantics: wave-uniform base + lane*16.
DEV void gload_lds16(const void* g, void* l) {
  __builtin_amdgcn_global_load_lds((__attribute__((address_space(1))) void*)g,
                                   (__attribute__((address_space(3))) void*)l,
                                   16, 0, 0);
}

// ---------------- prep kernels ----------------

// dst[n][k] = (bf16)src[k][n]; src is K x N row-major. block (32,8), grid (K/32, N/32)
__global__ void transpose_cast_k(const float* __restrict__ src, bf16* __restrict__ dst,
                                 int K, int N) {
  __shared__ float tile[32][33];
  int kb = blockIdx.x * 32, nb = blockIdx.y * 32;
  int tx = threadIdx.x, ty = threadIdx.y;
#pragma unroll
  for (int i = 0; i < 32; i += 8)
    tile[ty + i][tx] = src[(size_t)(kb + ty + i) * N + nb + tx];
  __syncthreads();
#pragma unroll
  for (int i = 0; i < 32; i += 8)
    dst[(size_t)(nb + ty + i) * K + kb + tx] = tobf(tile[tx][ty + i]);
}

// Wg (2048x16) -> WT rows: dst[r][k] = Wg[k][r]. grid 32 blocks: g=bx>>4, r=bx&15.
__global__ void gw_transpose_k(const float* __restrict__ Wg1, const float* __restrict__ Wg2,
                               bf16* __restrict__ dstbase) {
  int g = blockIdx.x >> 4, r = blockIdx.x & 15;
  const float* src = g ? Wg2 : Wg1;
  bf16* dst = dstbase + (size_t)(3072 + g * 16 + r) * 2048;
  for (int k = threadIdx.x; k < 2048; k += 256) dst[k] = tobf(src[(size_t)k * 16 + r]);
}

__global__ void cast_x_k(const float* __restrict__ src, bf16* __restrict__ dst) {
  int i = blockIdx.x * blockDim.x + threadIdx.x;  // one float4 per thread
  float4 v = ((const float4*)src)[i];
  bf16 t[4] = {tobf(v.x), tobf(v.y), tobf(v.z), tobf(v.w)};
  uint2 p; __builtin_memcpy(&p, t, 8);
  ((uint2*)dst)[i] = p;
}

// cos/sin tables: [S][64]. grid S blocks x 64 threads.
__global__ void rope_table_k(const int* __restrict__ pos, float* __restrict__ cosT,
                             float* __restrict__ sinT) {
  int s = blockIdx.x, i = threadIdx.x;
  double inv = exp(-((double)(2 * i) / 128.0) * log(10000.0));
  float f = (float)pos[s] * (float)inv;
  cosT[s * 64 + i] = cosf(f);
  sinT[s * 64 + i] = sinf(f);
}

// RoPE in place on qkv, vectorized 16B: thread = (token t, head 0..19, chunk c of 8 dims).
__global__ __launch_bounds__(256) void rope_apply_k(
    bf16* __restrict__ qkv, const float* __restrict__ cosT, const float* __restrict__ sinT) {
  int idx = blockIdx.x * 256 + threadIdx.x;  // 4096*20*8 = 655360
  int c = idx & 7, hh = idx >> 3;
  int head = hh % 20, t = hh / 20;
  int s = t & 2047;
  size_t base = (size_t)t * 3072 + (head < 16 ? head * 128 : 2048 + (head - 16) * 128);
  int d0 = c * 8;
  bf16x8 lo = *(const bf16x8*)(qkv + base + d0);
  bf16x8 hi = *(const bf16x8*)(qkv + base + d0 + 64);
  float4 c0 = *(const float4*)(cosT + s * 64 + d0);
  float4 c1 = *(const float4*)(cosT + s * 64 + d0 + 4);
  float4 s0 = *(const float4*)(sinT + s * 64 + d0);
  float4 s1 = *(const float4*)(sinT + s * 64 + d0 + 4);
  float cs[8] = {c0.x, c0.y, c0.z, c0.w, c1.x, c1.y, c1.z, c1.w};
  float sn[8] = {s0.x, s0.y, s0.z, s0.w, s1.x, s1.y, s1.z, s1.w};
  bf16x8 olo, ohi;
#pragma unroll
  for (int j = 0; j < 8; j++) {
    float a = tof(((const bf16*)&lo)[j]), b = tof(((const bf16*)&hi)[j]);
    ((bf16*)&olo)[j] = tobf(a * cs[j] - b * sn[j]);
    ((bf16*)&ohi)[j] = tobf(b * cs[j] + a * sn[j]);
  }
  *(bf16x8*)(qkv + base + d0) = olo;
  *(bf16x8*)(qkv + base + d0 + 64) = ohi;
}

// ---------------- QKV+gates GEMM: [qkv | g1 | g2] = Xbf @ WT^T ----------------
__global__ __launch_bounds__(256, 2) void gemm_qkv_k(
    const bf16* __restrict__ A, const bf16* __restrict__ Bt, bf16* __restrict__ qkv,
    float* __restrict__ g1, float* __restrict__ g2,
    const float* __restrict__ bg1, const float* __restrict__ bg2) {
  constexpr int BK = 32, K = 2048;
  __shared__ bf16 sA[2][128 * BK];
  __shared__ bf16 sB[2][128 * BK];
  const int tid = threadIdx.x, wave = tid >> 6, lane = tid & 63;
  const int lhi = lane >> 4, llo = lane & 15;
  const int wm = wave >> 1, wn = wave & 1;
  const int bm = blockIdx.y, bn = blockIdx.x;
  const bf16* Ag = A + (size_t)bm * 128 * K;
  const bf16* Bg = Bt + (size_t)bn * 128 * K;

  f32x4 acc[4][4];
#pragma unroll
  for (int m = 0; m < 4; m++)
#pragma unroll
    for (int n = 0; n < 4; n++) acc[m][n] = f32x4{0.f, 0.f, 0.f, 0.f};

  auto stage = [&](int buf, int kt) {
#pragma unroll
    for (int i = 0; i < 2; i++) {
      int c = i * 256 + tid, row = c >> 2, c8 = c & 3;
      gload_lds16(Ag + (size_t)row * K + kt * BK + c8 * 8, &sA[buf][c * 8]);
    }
#pragma unroll
    for (int i = 0; i < 2; i++) {
      int c = i * 256 + tid, row = c >> 2, c8 = c & 3;
      gload_lds16(Bg + (size_t)row * K + kt * BK + c8 * 8, &sB[buf][c * 8]);
    }
  };

  const int NT = K / BK;
  stage(0, 0);
  for (int kt = 0; kt < NT; kt++) {
    __syncthreads();
    if (kt + 1 < NT) stage((kt + 1) & 1, kt + 1);
    const bf16* a_ = sA[kt & 1];
    const bf16* b_ = sB[kt & 1];
    bf16x8 af[4], bfr[4];
#pragma unroll
    for (int m = 0; m < 4; m++)
      af[m] = *(const bf16x8*)&a_[(wm * 64 + m * 16 + llo) * BK + lhi * 8];
#pragma unroll
    for (int n = 0; n < 4; n++)
      bfr[n] = *(const bf16x8*)&b_[(wn * 64 + n * 16 + llo) * BK + lhi * 8];
#pragma unroll
    for (int m = 0; m < 4; m++)
#pragma unroll
      for (int n = 0; n < 4; n++)
        acc[m][n] = __builtin_amdgcn_mfma_f32_16x16x32_bf16(af[m], bfr[n], acc[m][n], 0, 0, 0);
  }

  const int r0 = bm * 128 + wm * 64, c0 = bn * 128 + wn * 64;
#pragma unroll
  for (int m = 0; m < 4; m++)
#pragma unroll
    for (int n = 0; n < 4; n++) {
      int col = c0 + n * 16 + llo;
#pragma unroll
      for (int r = 0; r < 4; r++) {
        int row = r0 + m * 16 + lhi * 4 + r;
        if (col < 3072) {
          qkv[(size_t)row * 3072 + col] = tobf(acc[m][n][r]);
        } else if (col < 3104) {
          int idx = col - 3072, hh = idx & 15;
          float b = (idx < 16) ? bg1[hh] : bg2[hh];
          float v = 1.f / (1.f + __expf(-(acc[m][n][r] + b)));
          ((idx < 16) ? g1 : g2)[(size_t)row * 16 + hh] = v;
        }
      }
    }
}

// ---------------- generic GEMM: C = A(MxK) * Bt(NxK)^T, fp32 out ----------------
__global__ __launch_bounds__(256, 2) void gemm_out_k(
    const bf16* __restrict__ A, const bf16* __restrict__ Bt, float* __restrict__ C,
    int M, int N, int K) {
  constexpr int BK = 32;
  __shared__ bf16 sA[2][128 * BK];
  __shared__ bf16 sB[2][128 * BK];
  const int tid = threadIdx.x, wave = tid >> 6, lane = tid & 63;
  const int lhi = lane >> 4, llo = lane & 15;
  const int wm = wave >> 1, wn = wave & 1;
  const int bm = blockIdx.y, bn = blockIdx.x;
  const bf16* Ag = A + (size_t)bm * 128 * K;
  const bf16* Bg = Bt + (size_t)bn * 128 * K;

  f32x4 acc[4][4];
#pragma unroll
  for (int m = 0; m < 4; m++)
#pragma unroll
    for (int n = 0; n < 4; n++) acc[m][n] = f32x4{0.f, 0.f, 0.f, 0.f};

  auto stage = [&](int buf, int kt) {
#pragma unroll
    for (int i = 0; i < 2; i++) {
      int c = i * 256 + tid, row = c >> 2, c8 = c & 3;
      gload_lds16(Ag + (size_t)row * K + kt * BK + c8 * 8, &sA[buf][c * 8]);
    }
#pragma unroll
    for (int i = 0; i < 2; i++) {
      int c = i * 256 + tid, row = c >> 2, c8 = c & 3;
      gload_lds16(Bg + (size_t)row * K + kt * BK + c8 * 8, &sB[buf][c * 8]);
    }
  };

  const int NT = K / BK;
  stage(0, 0);
  for (int kt = 0; kt < NT; kt++) {
    __syncthreads();
    if (kt + 1 < NT) stage((kt + 1) & 1, kt + 1);
    const bf16* a_ = sA[kt & 1];
    const bf16* b_ = sB[kt & 1];
    bf16x8 af[4], bfr[4];
#pragma unroll
    for (int m = 0; m < 4; m++)
      af[m] = *(const bf16x8*)&a_[(wm * 64 + m * 16 + llo) * BK + lhi * 8];
#pragma unroll
    for (int n = 0; n < 4; n++)
      bfr[n] = *(const bf16x8*)&b_[(wn * 64 + n * 16 + llo) * BK + lhi * 8];
#pragma unroll
    for (int m = 0; m < 4; m++)
#pragma unroll
      for (int n = 0; n < 4; n++)
        acc[m][n] = __builtin_amdgcn_mfma_f32_16x16x32_bf16(af[m], bfr[n], acc[m][n], 0, 0, 0);
  }

  const int r0 = bm * 128 + wm * 64, c0 = bn * 128 + wn * 64;
#pragma unroll
  for (int m = 0; m < 4; m++)
#pragma unroll
    for (int n = 0; n < 4; n++)
#pragma unroll
      for (int r = 0; r < 4; r++)
        C[(size_t)(r0 + m * 16 + lhi * 4 + r) * N + (c0 + n * 16 + llo)] = acc[m][n][r];
}

// ---------------- split-K causal GQA attention ----------------
// 2560 blocks = 32 (b,h) x 80 split-units. Split unit idx (longest-first order):
//   idx<32 : qt=31-(idx>>2), s=idx&3     (qt 24..31: 4 splits)
//   idx<56 : t=idx-32, qt=23-t/3, s=t%3  (qt 16..23: 3 splits)
//   idx<72 : t=idx-56, qt=15-(t>>1), s=t&1
//   else   : qt=7-(idx-72), s=0
// Split s covers kv tiles [8s, min(8s+8, qt+1)). Emits partial raw O (fp32), m, l.
__global__ __launch_bounds__(256, 3) void attn_split_k(
    const bf16* __restrict__ qkv, const float* __restrict__ g2,
    float* __restrict__ pO, float* __restrict__ pML) {
  constexpr int S = 2048, LD = 3072, NH = 16;
  const int bid = blockIdx.x;
  const int idx = bid >> 5, bh = bid & 31;
  int qt, s;
  if (idx < 32) { qt = 31 - (idx >> 2); s = idx & 3; }
  else if (idx < 56) { int t = idx - 32; qt = 23 - t / 3; s = t - (t / 3) * 3; }
  else if (idx < 72) { int t = idx - 56; qt = 15 - (t >> 1); s = t & 1; }
  else { qt = 7 - (idx - 72); s = 0; }
  const int k0 = s * 8, k1 = min(s * 8 + 8, qt + 1);

  const int b = bh >> 4, h = bh & 15, kvh = h >> 2;
  const int tid = threadIdx.x, wave = tid >> 6, lane = tid & 63;
  const int lhi = lane >> 4, llo = lane & 15;
  const size_t tok0 = (size_t)b * S;

  __shared__ bf16 sK[64 * 128];   // [kv][d], XOR-swizzled ((row&7)<<3 on element idx)
  __shared__ bf16 sV[128 * 64];   // [d][kv] transposed, XOR-swizzled ((d&7)<<3)
  __shared__ bf16 sP[4][16][72];  // per-wave P tile, padded

  const int qrow0 = qt * 64 + wave * 16;

  bf16x8 qf[4];
  {
    const bf16* qg = qkv + (tok0 + qrow0 + llo) * LD + h * 128;
#pragma unroll
    for (int dc = 0; dc < 4; dc++) qf[dc] = *(const bf16x8*)(qg + dc * 32 + lhi * 8);
  }

  f32x4 oacc[8];
#pragma unroll
  for (int i = 0; i < 8; i++) oacc[i] = f32x4{0.f, 0.f, 0.f, 0.f};
  float mrow[4] = {-1e30f, -1e30f, -1e30f, -1e30f};
  float lrow[4] = {0.f, 0.f, 0.f, 0.f};
  const float scale = 0.08838834764831845f;  // 1/sqrt(128)

  uint4 kreg[4];
  bf16x8 vreg[4];
  float gvreg;
  const int vdg = tid >> 4;   // d-group: 8 d elems
  const int vkg = tid & 15;   // kv-group: 4 kv rows

  auto issue_loads = [&](int kt) {
#pragma unroll
    for (int i = 0; i < 4; i++) {
      int c = i * 256 + tid, row = c >> 4, c8 = c & 15;
      kreg[i] = *(const uint4*)(qkv + (tok0 + kt * 64 + row) * LD + 2048 + kvh * 128 + c8 * 8);
    }
#pragma unroll
    for (int r = 0; r < 4; r++)
      vreg[r] = *(const bf16x8*)(qkv + (tok0 + kt * 64 + vkg * 4 + r) * LD + 2560 +
                                 kvh * 128 + vdg * 8);
    gvreg = g2[(tok0 + kt * 64 + lane) * NH + h];  // prefetched with K/V (T14)
  };

  auto write_lds = [&]() {
#pragma unroll
    for (int i = 0; i < 4; i++) {
      int c = i * 256 + tid, row = c >> 4, c8 = c & 15;
      int eidx = (row * 128 + c8 * 8) ^ ((row & 7) << 3);
      *(uint4*)&sK[eidx] = kreg[i];
    }
#pragma unroll
    for (int e = 0; e < 8; e++) {
      int d = vdg * 8 + e;          // d & 7 == e
      uint32_t lo = (uint32_t)(unsigned short)vreg[0][e] |
                    ((uint32_t)(unsigned short)vreg[1][e] << 16);
      uint32_t hi = (uint32_t)(unsigned short)vreg[2][e] |
                    ((uint32_t)(unsigned short)vreg[3][e] << 16);
      int eidx = (d * 64 + vkg * 4) ^ (e << 3);
      uint2 pk; pk.x = lo; pk.y = hi;
      *(uint2*)&sV[eidx] = pk;
    }
  };

  issue_loads(k0);
  for (int kt = k0; kt < k1; kt++) {
    __syncthreads();  // previous tile's LDS reads complete before overwrite
    write_lds();      // vmcnt wait for kreg/vreg/gvreg lands here (data long arrived)
    float gv = gvreg;
    __syncthreads();  // LDS writes visible
    if (kt + 1 < k1) issue_loads(kt + 1);  // in flight during compute below (T14)

    const bool diag = (kt == qt);
    // ---- QK^T ----
    f32x4 sc[4];
#pragma unroll
    for (int ct = 0; ct < 4; ct++) {
      f32x4 acc = f32x4{0.f, 0.f, 0.f, 0.f};
#pragma unroll
      for (int dc = 0; dc < 4; dc++) {
        int row = ct * 16 + llo;
        bf16x8 kf = *(const bf16x8*)&sK[(row * 128 + dc * 32 + lhi * 8) ^ ((row & 7) << 3)];
        acc = __builtin_amdgcn_mfma_f32_16x16x32_bf16(qf[dc], kf, acc, 0, 0, 0);
      }
      sc[ct] = acc;
    }
    // ---- scale + causal mask + online softmax ----
    float pm[4] = {-1e30f, -1e30f, -1e30f, -1e30f};
#pragma unroll
    for (int ct = 0; ct < 4; ct++) {
      int kv = kt * 64 + ct * 16 + llo;
#pragma unroll
      for (int r = 0; r < 4; r++) {
        float s_ = sc[ct][r] * scale;
        if (diag && kv > qrow0 + lhi * 4 + r) s_ = -1e30f;
        sc[ct][r] = s_;
        pm[r] = fmaxf(pm[r], s_);
      }
    }
#pragma unroll
    for (int r = 0; r < 4; r++) {
      float v = pm[r];
      v = fmaxf(v, __shfl_xor(v, 1));
      v = fmaxf(v, __shfl_xor(v, 2));
      v = fmaxf(v, __shfl_xor(v, 4));
      v = fmaxf(v, __shfl_xor(v, 8));
      float mnew = fmaxf(mrow[r], v);
      float al = __expf(mrow[r] - mnew);
      mrow[r] = mnew;
      lrow[r] *= al;
#pragma unroll
      for (int i = 0; i < 8; i++) oacc[i][r] *= al;
    }
    float g2v[4];
#pragma unroll
    for (int ct = 0; ct < 4; ct++) g2v[ct] = __shfl(gv, ct * 16 + llo);
    float rs[4] = {0.f, 0.f, 0.f, 0.f};
#pragma unroll
    for (int ct = 0; ct < 4; ct++) {
#pragma unroll
      for (int r = 0; r < 4; r++) {
        float p = __expf(sc[ct][r] - mrow[r]);
        rs[r] += p;  // softmax denom uses UNGATED p
        sP[wave][lhi * 4 + r][ct * 16 + llo] = tobf(p * g2v[ct]);
      }
    }
#pragma unroll
    for (int r = 0; r < 4; r++) {
      float v = rs[r];
      v += __shfl_xor(v, 1); v += __shfl_xor(v, 2); v += __shfl_xor(v, 4); v += __shfl_xor(v, 8);
      lrow[r] += v;
    }
    // ---- PV: O += (P*g2) * V ----
#pragma unroll
    for (int kc = 0; kc < 2; kc++) {
      bf16x8 pf = *(const bf16x8*)&sP[wave][llo][kc * 32 + lhi * 8];
#pragma unroll
      for (int dt = 0; dt < 8; dt++) {
        int d = dt * 16 + llo;
        bf16x8 vf = *(const bf16x8*)&sV[(d * 64 + kc * 32 + lhi * 8) ^ ((d & 7) << 3)];
        oacc[dt] = __builtin_amdgcn_mfma_f32_16x16x32_bf16(pf, vf, oacc[dt], 0, 0, 0);
      }
    }
  }

  // ---- emit partials: raw O (fp32), m, l ----
#pragma unroll
  for (int dt = 0; dt < 8; dt++)
#pragma unroll
    for (int r = 0; r < 4; r++)
      pO[(size_t)bid * 8192 + (wave * 16 + lhi * 4 + r) * 128 + dt * 16 + llo] = oacc[dt][r];
  if (llo == 0) {
#pragma unroll
    for (int r = 0; r < 4; r++) {
      int row2 = wave * 16 + lhi * 4 + r;
      pML[(size_t)bid * 128 + row2 * 2]     = mrow[r];
      pML[(size_t)bid * 128 + row2 * 2 + 1] = lrow[r];
    }
  }
}

// ---------------- combine partials + LayerNorm + g1 gate ----------------
// grid 1024 = 32 qt x 32 bh. Thread t: row r=t>>2 (64 rows), quad q=t&3 (32 d each).
__global__ __launch_bounds__(256) void attn_combine_k(
    const float* __restrict__ pO, const float* __restrict__ pML,
    const float* __restrict__ g1, const float* __restrict__ lng,
    const float* __restrict__ lnb, bf16* __restrict__ aout) {
  const int bx = blockIdx.x;
  const int qt = bx >> 5, bh = bx & 31;
  const int b = bh >> 4, h = bh & 15;
  const int t = threadIdx.x, r = t >> 2, q = t & 3;
  const int nsplit = (qt + 8) >> 3;  // ceil((qt+1)/8)
  int base;
  if (qt >= 24) base = (31 - qt) * 4;
  else if (qt >= 16) base = 32 + (23 - qt) * 3;
  else if (qt >= 8) base = 56 + (15 - qt) * 2;
  else base = 72 + (7 - qt);

  float m[4] = {-1e30f, -1e30f, -1e30f, -1e30f};
  float l[4] = {0.f, 0.f, 0.f, 0.f};
  float mstar = -1e30f;
#pragma unroll
  for (int s = 0; s < 4; s++)
    if (s < nsplit) {
      int pb = (base + s) * 32 + bh;
      m[s] = pML[(size_t)pb * 128 + r * 2];
      l[s] = pML[(size_t)pb * 128 + r * 2 + 1];
      mstar = fmaxf(mstar, m[s]);
    }
  float w[4] = {0.f, 0.f, 0.f, 0.f};
  float L = 0.f;
#pragma unroll
  for (int s = 0; s < 4; s++)
    if (s < nsplit) { w[s] = __expf(m[s] - mstar); L += w[s] * l[s]; }
  const float invL = 1.f / L;

  float ov[32];
  float sum = 0.f, sq = 0.f;
#pragma unroll
  for (int j = 0; j < 8; j++) {
    int d = q * 32 + j * 4;
    float4 a = {0.f, 0.f, 0.f, 0.f};
#pragma unroll
    for (int s = 0; s < 4; s++)
      if (s < nsplit) {
        int pb = (base + s) * 32 + bh;
        float4 o = *(const float4*)&pO[(size_t)pb * 8192 + r * 128 + d];
        a.x += w[s] * o.x; a.y += w[s] * o.y; a.z += w[s] * o.z; a.w += w[s] * o.w;
      }
    a.x *= invL; a.y *= invL; a.z *= invL; a.w *= invL;
    ov[j * 4] = a.x; ov[j * 4 + 1] = a.y; ov[j * 4 + 2] = a.z; ov[j * 4 + 3] = a.w;
    sum += a.x + a.y + a.z + a.w;
    sq += a.x * a.x + a.y * a.y + a.z * a.z + a.w * a.w;
  }
  sum += __shfl_xor(sum, 1); sum += __shfl_xor(sum, 2);
  sq  += __shfl_xor(sq, 1);  sq  += __shfl_xor(sq, 2);
  const float mu = sum * (1.f / 128.f);
  const float var = sq * (1.f / 128.f) - mu * mu;
  const float rstd = rsqrtf(var + 1e-5f);

  const int qrow = qt * 64 + r;
  const size_t tok = (size_t)b * 2048 + qrow;
  const float gg = g1[tok * 16 + h];
  bf16* og = aout + tok * 2048 + h * 128 + q * 32;
#pragma unroll
  for (int j8 = 0; j8 < 4; j8++) {
    bf16x8 o8;
#pragma unroll
    for (int jj = 0; jj < 8; jj++) {
      int d = q * 32 + j8 * 8 + jj;
      float v = (ov[j8 * 8 + jj] - mu) * rstd * lng[d] + lnb[d];
      ((bf16*)&o8)[jj] = tobf(v * gg);
    }
    *(bf16x8*)(og + j8 * 8) = o8;
  }
}

// ---------------- launch ----------------
extern "C" void kernel_launch(void* const* d_in, const int* in_sizes, int n_in,
                              void* d_out, int out_size, void* d_ws, size_t ws_size,
                              hipStream_t stream) {
  (void)in_sizes; (void)n_in; (void)out_size; (void)ws_size;
  const float* X   = (const float*)d_in[0];
  const int*   pos = (const int*)d_in[1];
  const float* Wq  = (const float*)d_in[2];
  const float* Wk  = (const float*)d_in[3];
  const float* Wv  = (const float*)d_in[4];
  const float* Wo  = (const float*)d_in[5];
  const float* Wg1 = (const float*)d_in[6];
  const float* bg1 = (const float*)d_in[7];
  const float* Wg2 = (const float*)d_in[8];
  const float* bg2 = (const float*)d_in[9];
  const float* lng = (const float*)d_in[10];
  const float* lnb = (const float*)d_in[11];

  char* ws = (char*)d_ws;
  size_t off = 0;
  auto alloc = [&](size_t bytes) {
    void* p = ws + off;
    off += (bytes + 255) & ~(size_t)255;
    return p;
  };
  bf16*  WT   = (bf16*)alloc(3200ull * 2048 * 2);   // [Wq^T; Wk^T; Wv^T; Wg1^T; Wg2^T; pad]
  bf16*  WoT  = (bf16*)alloc(2048ull * 2048 * 2);
  bf16*  Xbf  = (bf16*)alloc(4096ull * 2048 * 2);
  bf16*  qkv  = (bf16*)alloc(4096ull * 3072 * 2);
  bf16*  attn = (bf16*)alloc(4096ull * 2048 * 2);
  float* cosT = (float*)alloc(2048ull * 64 * 4);
  float* sinT = (float*)alloc(2048ull * 64 * 4);
  float* g1   = (float*)alloc(4096ull * 16 * 4);
  float* g2   = (float*)alloc(4096ull * 16 * 4);
  float* pO   = (float*)alloc(2560ull * 8192 * 4);  // split partial O (raw)
  float* pML  = (float*)alloc(2560ull * 128 * 4);   // split partial m,l

  dim3 tb(32, 8);
  transpose_cast_k<<<dim3(64, 64), tb, 0, stream>>>(Wq, WT, 2048, 2048);
  transpose_cast_k<<<dim3(64, 16), tb, 0, stream>>>(Wk, WT + 2048ull * 2048, 2048, 512);
  transpose_cast_k<<<dim3(64, 16), tb, 0, stream>>>(Wv, WT + 2560ull * 2048, 2048, 512);
  transpose_cast_k<<<dim3(64, 64), tb, 0, stream>>>(Wo, WoT, 2048, 2048);
  gw_transpose_k<<<32, 256, 0, stream>>>(Wg1, Wg2, WT);
  cast_x_k<<<8192, 256, 0, stream>>>(X, Xbf);
  rope_table_k<<<2048, 64, 0, stream>>>(pos, cosT, sinT);

  // [qkv | g1 | g2] = Xbf @ WT^T  (4096 x 3200)
  gemm_qkv_k<<<dim3(25, 32), 256, 0, stream>>>(Xbf, WT, qkv, g1, g2, bg1, bg2);
  rope_apply_k<<<2560, 256, 0, stream>>>(qkv, cosT, sinT);
  attn_split_k<<<2560, 256, 0, stream>>>(qkv, g2, pO, pML);
  attn_combine_k<<<1024, 256, 0, stream>>>(pO, pML, g1, lng, lnb, attn);
  // out = attn @ Wo  (4096 x 2048), fp32
  gemm_out_k<<<dim3(16, 32), 256, 0, stream>>>(attn, WoT, (float*)d_out, 4096, 2048, 2048);
}

// Round 6
// 447.119 us; speedup vs baseline: 1.0327x; 1.0327x over previous
//
#include <hip/hip_runtime.h>
#include <hip/hip_bf16.h>
#include <stdint.h>
#include <string.h>

using bf16 = __hip_bfloat16;
typedef __attribute__((ext_vector_type(8))) short bf16x8;   // 8 bf16 (4 VGPRs) MFMA A/B frag
typedef __attribute__((ext_vector_type(4))) float f32x4;    // MFMA C/D frag

#define DEV static __device__ __forceinline__

DEV bf16 tobf(float f) { return __float2bfloat16(f); }
DEV float tof(bf16 h) { return __bfloat162float(h); }

// async global->LDS, 16B per lane. LDS dest semantics: wave-uniform base + lane*16.
DEV void gload_lds16(const void* g, void* l) {
  __builtin_amdgcn_global_load_lds((__attribute__((address_space(1))) void*)g,
                                   (__attribute__((address_space(3))) void*)l,
                                   16, 0, 0);
}

// ---------------- prep kernels ----------------

// dst[n][k] = (bf16)src[k][n]; src is K x N row-major. block (32,8), grid (K/32, N/32)
__global__ void transpose_cast_k(const float* __restrict__ src, bf16* __restrict__ dst,
                                 int K, int N) {
  __shared__ float tile[32][33];
  int kb = blockIdx.x * 32, nb = blockIdx.y * 32;
  int tx = threadIdx.x, ty = threadIdx.y;
#pragma unroll
  for (int i = 0; i < 32; i += 8)
    tile[ty + i][tx] = src[(size_t)(kb + ty + i) * N + nb + tx];
  __syncthreads();
#pragma unroll
  for (int i = 0; i < 32; i += 8)
    dst[(size_t)(nb + ty + i) * K + kb + tx] = tobf(tile[tx][ty + i]);
}

// Wg (2048x16) -> WT rows: dst[r][k] = Wg[k][r]. grid 32 blocks: g=bx>>4, r=bx&15.
__global__ void gw_transpose_k(const float* __restrict__ Wg1, const float* __restrict__ Wg2,
                               bf16* __restrict__ dstbase) {
  int g = blockIdx.x >> 4, r = blockIdx.x & 15;
  const float* src = g ? Wg2 : Wg1;
  bf16* dst = dstbase + (size_t)(3072 + g * 16 + r) * 2048;
  for (int k = threadIdx.x; k < 2048; k += 256) dst[k] = tobf(src[(size_t)k * 16 + r]);
}

__global__ void cast_x_k(const float* __restrict__ src, bf16* __restrict__ dst) {
  int i = blockIdx.x * blockDim.x + threadIdx.x;  // one float4 per thread
  float4 v = ((const float4*)src)[i];
  bf16 t[4] = {tobf(v.x), tobf(v.y), tobf(v.z), tobf(v.w)};
  uint2 p; __builtin_memcpy(&p, t, 8);
  ((uint2*)dst)[i] = p;
}

// cos/sin tables: [S][64]. grid S blocks x 64 threads.
__global__ void rope_table_k(const int* __restrict__ pos, float* __restrict__ cosT,
                             float* __restrict__ sinT) {
  int s = blockIdx.x, i = threadIdx.x;
  double inv = exp(-((double)(2 * i) / 128.0) * log(10000.0));
  float f = (float)pos[s] * (float)inv;
  cosT[s * 64 + i] = cosf(f);
  sinT[s * 64 + i] = sinf(f);
}

// RoPE in place on qkv, vectorized 16B: thread = (token t, head 0..19, chunk c of 8 dims).
__global__ __launch_bounds__(256) void rope_apply_k(
    bf16* __restrict__ qkv, const float* __restrict__ cosT, const float* __restrict__ sinT) {
  int idx = blockIdx.x * 256 + threadIdx.x;  // 4096*20*8 = 655360
  int c = idx & 7, hh = idx >> 3;
  int head = hh % 20, t = hh / 20;
  int s = t & 2047;
  size_t base = (size_t)t * 3072 + (head < 16 ? head * 128 : 2048 + (head - 16) * 128);
  int d0 = c * 8;
  bf16x8 lo = *(const bf16x8*)(qkv + base + d0);
  bf16x8 hi = *(const bf16x8*)(qkv + base + d0 + 64);
  float4 c0 = *(const float4*)(cosT + s * 64 + d0);
  float4 c1 = *(const float4*)(cosT + s * 64 + d0 + 4);
  float4 s0 = *(const float4*)(sinT + s * 64 + d0);
  float4 s1 = *(const float4*)(sinT + s * 64 + d0 + 4);
  float cs[8] = {c0.x, c0.y, c0.z, c0.w, c1.x, c1.y, c1.z, c1.w};
  float sn[8] = {s0.x, s0.y, s0.z, s0.w, s1.x, s1.y, s1.z, s1.w};
  bf16x8 olo, ohi;
#pragma unroll
  for (int j = 0; j < 8; j++) {
    float a = tof(((const bf16*)&lo)[j]), b = tof(((const bf16*)&hi)[j]);
    ((bf16*)&olo)[j] = tobf(a * cs[j] - b * sn[j]);
    ((bf16*)&ohi)[j] = tobf(b * cs[j] + a * sn[j]);
  }
  *(bf16x8*)(qkv + base + d0) = olo;
  *(bf16x8*)(qkv + base + d0 + 64) = ohi;
}

// ---------------- QKV+gates GEMM: [qkv | g1t | g2t] = Xbf @ WT^T ----------------
// Gates written TRANSPOSED: g1t/g2t are [16][4096] fp32 (head-major), so attention's
// per-tile gate load is one contiguous 256B wave load instead of a 64-line gather.
__global__ __launch_bounds__(256, 2) void gemm_qkv_k(
    const bf16* __restrict__ A, const bf16* __restrict__ Bt, bf16* __restrict__ qkv,
    float* __restrict__ g1t, float* __restrict__ g2t,
    const float* __restrict__ bg1, const float* __restrict__ bg2) {
  constexpr int BK = 32, K = 2048;
  __shared__ bf16 sA[2][128 * BK];
  __shared__ bf16 sB[2][128 * BK];
  const int tid = threadIdx.x, wave = tid >> 6, lane = tid & 63;
  const int lhi = lane >> 4, llo = lane & 15;
  const int wm = wave >> 1, wn = wave & 1;
  const int bm = blockIdx.y, bn = blockIdx.x;
  const bf16* Ag = A + (size_t)bm * 128 * K;
  const bf16* Bg = Bt + (size_t)bn * 128 * K;

  f32x4 acc[4][4];
#pragma unroll
  for (int m = 0; m < 4; m++)
#pragma unroll
    for (int n = 0; n < 4; n++) acc[m][n] = f32x4{0.f, 0.f, 0.f, 0.f};

  auto stage = [&](int buf, int kt) {
#pragma unroll
    for (int i = 0; i < 2; i++) {
      int c = i * 256 + tid, row = c >> 2, c8 = c & 3;
      gload_lds16(Ag + (size_t)row * K + kt * BK + c8 * 8, &sA[buf][c * 8]);
    }
#pragma unroll
    for (int i = 0; i < 2; i++) {
      int c = i * 256 + tid, row = c >> 2, c8 = c & 3;
      gload_lds16(Bg + (size_t)row * K + kt * BK + c8 * 8, &sB[buf][c * 8]);
    }
  };

  const int NT = K / BK;
  stage(0, 0);
  for (int kt = 0; kt < NT; kt++) {
    __syncthreads();
    if (kt + 1 < NT) stage((kt + 1) & 1, kt + 1);
    const bf16* a_ = sA[kt & 1];
    const bf16* b_ = sB[kt & 1];
    bf16x8 af[4], bfr[4];
#pragma unroll
    for (int m = 0; m < 4; m++)
      af[m] = *(const bf16x8*)&a_[(wm * 64 + m * 16 + llo) * BK + lhi * 8];
#pragma unroll
    for (int n = 0; n < 4; n++)
      bfr[n] = *(const bf16x8*)&b_[(wn * 64 + n * 16 + llo) * BK + lhi * 8];
#pragma unroll
    for (int m = 0; m < 4; m++)
#pragma unroll
      for (int n = 0; n < 4; n++)
        acc[m][n] = __builtin_amdgcn_mfma_f32_16x16x32_bf16(af[m], bfr[n], acc[m][n], 0, 0, 0);
  }

  const int r0 = bm * 128 + wm * 64, c0 = bn * 128 + wn * 64;
#pragma unroll
  for (int m = 0; m < 4; m++)
#pragma unroll
    for (int n = 0; n < 4; n++) {
      int col = c0 + n * 16 + llo;
#pragma unroll
      for (int r = 0; r < 4; r++) {
        int row = r0 + m * 16 + lhi * 4 + r;
        if (col < 3072) {
          qkv[(size_t)row * 3072 + col] = tobf(acc[m][n][r]);
        } else if (col < 3104) {
          int idx = col - 3072, hh = idx & 15;
          float b = (idx < 16) ? bg1[hh] : bg2[hh];
          float v = 1.f / (1.f + __expf(-(acc[m][n][r] + b)));
          ((idx < 16) ? g1t : g2t)[(size_t)hh * 4096 + row] = v;
        }
      }
    }
}

// ---------------- generic GEMM: C = A(MxK) * Bt(NxK)^T, fp32 out ----------------
__global__ __launch_bounds__(256, 2) void gemm_out_k(
    const bf16* __restrict__ A, const bf16* __restrict__ Bt, float* __restrict__ C,
    int M, int N, int K) {
  constexpr int BK = 32;
  __shared__ bf16 sA[2][128 * BK];
  __shared__ bf16 sB[2][128 * BK];
  const int tid = threadIdx.x, wave = tid >> 6, lane = tid & 63;
  const int lhi = lane >> 4, llo = lane & 15;
  const int wm = wave >> 1, wn = wave & 1;
  const int bm = blockIdx.y, bn = blockIdx.x;
  const bf16* Ag = A + (size_t)bm * 128 * K;
  const bf16* Bg = Bt + (size_t)bn * 128 * K;

  f32x4 acc[4][4];
#pragma unroll
  for (int m = 0; m < 4; m++)
#pragma unroll
    for (int n = 0; n < 4; n++) acc[m][n] = f32x4{0.f, 0.f, 0.f, 0.f};

  auto stage = [&](int buf, int kt) {
#pragma unroll
    for (int i = 0; i < 2; i++) {
      int c = i * 256 + tid, row = c >> 2, c8 = c & 3;
      gload_lds16(Ag + (size_t)row * K + kt * BK + c8 * 8, &sA[buf][c * 8]);
    }
#pragma unroll
    for (int i = 0; i < 2; i++) {
      int c = i * 256 + tid, row = c >> 2, c8 = c & 3;
      gload_lds16(Bg + (size_t)row * K + kt * BK + c8 * 8, &sB[buf][c * 8]);
    }
  };

  const int NT = K / BK;
  stage(0, 0);
  for (int kt = 0; kt < NT; kt++) {
    __syncthreads();
    if (kt + 1 < NT) stage((kt + 1) & 1, kt + 1);
    const bf16* a_ = sA[kt & 1];
    const bf16* b_ = sB[kt & 1];
    bf16x8 af[4], bfr[4];
#pragma unroll
    for (int m = 0; m < 4; m++)
      af[m] = *(const bf16x8*)&a_[(wm * 64 + m * 16 + llo) * BK + lhi * 8];
#pragma unroll
    for (int n = 0; n < 4; n++)
      bfr[n] = *(const bf16x8*)&b_[(wn * 64 + n * 16 + llo) * BK + lhi * 8];
#pragma unroll
    for (int m = 0; m < 4; m++)
#pragma unroll
      for (int n = 0; n < 4; n++)
        acc[m][n] = __builtin_amdgcn_mfma_f32_16x16x32_bf16(af[m], bfr[n], acc[m][n], 0, 0, 0);
  }

  const int r0 = bm * 128 + wm * 64, c0 = bn * 128 + wn * 64;
#pragma unroll
  for (int m = 0; m < 4; m++)
#pragma unroll
    for (int n = 0; n < 4; n++)
#pragma unroll
      for (int r = 0; r < 4; r++)
        C[(size_t)(r0 + m * 16 + lhi * 4 + r) * N + (c0 + n * 16 + llo)] = acc[m][n][r];
}

// ---------------- split-K causal GQA attention, XCD-grouped ----------------
// bid = (u*4 + h_in)*8 + g, g = b*4+kvh. Default dispatch round-robins bid%8 -> XCD,
// so ALL blocks of one (b,kvh) group land on one XCD; that group's K+V (1 MB) becomes
// L2-resident -> kills the 540 MB K/V re-fetch stream seen in R5.
// u (split unit, longest-first): u<32: qt=31-(u>>2),s=u&3; u<56: qt=23-(u-32)/3,s=(u-32)%3;
// u<72: qt=15-((u-56)>>1),s=(u-56)&1; else qt=7-(u-72),s=0. kv tiles [8s, min(8s+8,qt+1)).
__global__ __launch_bounds__(256, 3) void attn_split_k(
    const bf16* __restrict__ qkv, const float* __restrict__ g2t,
    float* __restrict__ pO, float* __restrict__ pML) {
  constexpr int S = 2048, LD = 3072;
  const int bid = blockIdx.x;
  const int g = bid & 7, j = bid >> 3;
  const int h_in = j & 3, u = j >> 2;
  int qt, s;
  if (u < 32) { qt = 31 - (u >> 2); s = u & 3; }
  else if (u < 56) { int t2 = u - 32; qt = 23 - t2 / 3; s = t2 - (t2 / 3) * 3; }
  else if (u < 72) { int t2 = u - 56; qt = 15 - (t2 >> 1); s = t2 & 1; }
  else { qt = 7 - (u - 72); s = 0; }
  const int k0 = s * 8, k1 = min(s * 8 + 8, qt + 1);

  const int b = g >> 2, kvh = g & 3, h = kvh * 4 + h_in;
  const int tid = threadIdx.x, wave = tid >> 6, lane = tid & 63;
  const int lhi = lane >> 4, llo = lane & 15;
  const size_t tok0 = (size_t)b * S;

  __shared__ bf16 sK[64 * 128];   // [kv][d], XOR-swizzled ((row&7)<<3 on element idx)
  __shared__ bf16 sV[128 * 64];   // [d][kv] transposed, XOR-swizzled ((d&7)<<3)
  __shared__ bf16 sP[4][16][72];  // per-wave P tile, padded

  const int qrow0 = qt * 64 + wave * 16;

  bf16x8 qf[4];
  {
    const bf16* qg = qkv + (tok0 + qrow0 + llo) * LD + h * 128;
#pragma unroll
    for (int dc = 0; dc < 4; dc++) qf[dc] = *(const bf16x8*)(qg + dc * 32 + lhi * 8);
  }

  f32x4 oacc[8];
#pragma unroll
  for (int i = 0; i < 8; i++) oacc[i] = f32x4{0.f, 0.f, 0.f, 0.f};
  float mrow[4] = {-1e30f, -1e30f, -1e30f, -1e30f};
  float lrow[4] = {0.f, 0.f, 0.f, 0.f};
  const float scale = 0.08838834764831845f;  // 1/sqrt(128)

  uint4 kreg[4];
  bf16x8 vreg[4];
  float gvreg;
  const int vdg = tid >> 4;   // d-group: 8 d elems
  const int vkg = tid & 15;   // kv-group: 4 kv rows

  auto issue_loads = [&](int kt) {
#pragma unroll
    for (int i = 0; i < 4; i++) {
      int c = i * 256 + tid, row = c >> 4, c8 = c & 15;
      kreg[i] = *(const uint4*)(qkv + (tok0 + kt * 64 + row) * LD + 2048 + kvh * 128 + c8 * 8);
    }
#pragma unroll
    for (int r = 0; r < 4; r++)
      vreg[r] = *(const bf16x8*)(qkv + (tok0 + kt * 64 + vkg * 4 + r) * LD + 2560 +
                                 kvh * 128 + vdg * 8);
    // contiguous 256B wave load (g2t is head-major)
    gvreg = g2t[(size_t)h * 4096 + tok0 + kt * 64 + lane];
  };

  auto write_lds = [&]() {
#pragma unroll
    for (int i = 0; i < 4; i++) {
      int c = i * 256 + tid, row = c >> 4, c8 = c & 15;
      int eidx = (row * 128 + c8 * 8) ^ ((row & 7) << 3);
      *(uint4*)&sK[eidx] = kreg[i];
    }
#pragma unroll
    for (int e = 0; e < 8; e++) {
      int d = vdg * 8 + e;          // d & 7 == e
      uint32_t lo = (uint32_t)(unsigned short)vreg[0][e] |
                    ((uint32_t)(unsigned short)vreg[1][e] << 16);
      uint32_t hi = (uint32_t)(unsigned short)vreg[2][e] |
                    ((uint32_t)(unsigned short)vreg[3][e] << 16);
      int eidx = (d * 64 + vkg * 4) ^ (e << 3);
      uint2 pk; pk.x = lo; pk.y = hi;
      *(uint2*)&sV[eidx] = pk;
    }
  };

  issue_loads(k0);
  for (int kt = k0; kt < k1; kt++) {
    __syncthreads();  // previous tile's LDS reads complete before overwrite
    write_lds();      // vmcnt wait for kreg/vreg/gvreg lands here (data long arrived)
    float gv = gvreg;
    __syncthreads();  // LDS writes visible
    if (kt + 1 < k1) issue_loads(kt + 1);  // in flight during compute below (T14)

    const bool diag = (kt == qt);
    // ---- QK^T ----
    f32x4 sc[4];
#pragma unroll
    for (int ct = 0; ct < 4; ct++) {
      f32x4 acc = f32x4{0.f, 0.f, 0.f, 0.f};
#pragma unroll
      for (int dc = 0; dc < 4; dc++) {
        int row = ct * 16 + llo;
        bf16x8 kf = *(const bf16x8*)&sK[(row * 128 + dc * 32 + lhi * 8) ^ ((row & 7) << 3)];
        acc = __builtin_amdgcn_mfma_f32_16x16x32_bf16(qf[dc], kf, acc, 0, 0, 0);
      }
      sc[ct] = acc;
    }
    // ---- scale + causal mask + online softmax ----
    float pm[4] = {-1e30f, -1e30f, -1e30f, -1e30f};
#pragma unroll
    for (int ct = 0; ct < 4; ct++) {
      int kv = kt * 64 + ct * 16 + llo;
#pragma unroll
      for (int r = 0; r < 4; r++) {
        float s_ = sc[ct][r] * scale;
        if (diag && kv > qrow0 + lhi * 4 + r) s_ = -1e30f;
        sc[ct][r] = s_;
        pm[r] = fmaxf(pm[r], s_);
      }
    }
#pragma unroll
    for (int r = 0; r < 4; r++) {
      float v = pm[r];
      v = fmaxf(v, __shfl_xor(v, 1));
      v = fmaxf(v, __shfl_xor(v, 2));
      v = fmaxf(v, __shfl_xor(v, 4));
      v = fmaxf(v, __shfl_xor(v, 8));
      pm[r] = v;  // tile max, uniform within llo-group
    }
    // exact defer-max: rescale only if some row's max grew (wave-uniform branch)
    int need = 0;
#pragma unroll
    for (int r = 0; r < 4; r++) need |= (pm[r] > mrow[r]) ? 1 : 0;
    if (__any(need)) {
#pragma unroll
      for (int r = 0; r < 4; r++) {
        float mnew = fmaxf(mrow[r], pm[r]);
        float al = __expf(mrow[r] - mnew);
        mrow[r] = mnew;
        lrow[r] *= al;
#pragma unroll
        for (int i = 0; i < 8; i++) oacc[i][r] *= al;
      }
    }
    float g2v[4];
#pragma unroll
    for (int ct = 0; ct < 4; ct++) g2v[ct] = __shfl(gv, ct * 16 + llo);
    float rs[4] = {0.f, 0.f, 0.f, 0.f};
#pragma unroll
    for (int ct = 0; ct < 4; ct++) {
#pragma unroll
      for (int r = 0; r < 4; r++) {
        float p = __expf(sc[ct][r] - mrow[r]);
        rs[r] += p;  // softmax denom uses UNGATED p
        sP[wave][lhi * 4 + r][ct * 16 + llo] = tobf(p * g2v[ct]);
      }
    }
#pragma unroll
    for (int r = 0; r < 4; r++) {
      float v = rs[r];
      v += __shfl_xor(v, 1); v += __shfl_xor(v, 2); v += __shfl_xor(v, 4); v += __shfl_xor(v, 8);
      lrow[r] += v;
    }
    // ---- PV: O += (P*g2) * V ----
#pragma unroll
    for (int kc = 0; kc < 2; kc++) {
      bf16x8 pf = *(const bf16x8*)&sP[wave][llo][kc * 32 + lhi * 8];
#pragma unroll
      for (int dt = 0; dt < 8; dt++) {
        int d = dt * 16 + llo;
        bf16x8 vf = *(const bf16x8*)&sV[(d * 64 + kc * 32 + lhi * 8) ^ ((d & 7) << 3)];
        oacc[dt] = __builtin_amdgcn_mfma_f32_16x16x32_bf16(pf, vf, oacc[dt], 0, 0, 0);
      }
    }
  }

  // ---- emit partials: raw O (fp32), m, l ----
#pragma unroll
  for (int dt = 0; dt < 8; dt++)
#pragma unroll
    for (int r = 0; r < 4; r++)
      pO[(size_t)bid * 8192 + (wave * 16 + lhi * 4 + r) * 128 + dt * 16 + llo] = oacc[dt][r];
  if (llo == 0) {
#pragma unroll
    for (int r = 0; r < 4; r++) {
      int row2 = wave * 16 + lhi * 4 + r;
      pML[(size_t)bid * 128 + row2 * 2]     = mrow[r];
      pML[(size_t)bid * 128 + row2 * 2 + 1] = lrow[r];
    }
  }
}

// ---------------- combine partials + LayerNorm + g1 gate, XCD-grouped ----------------
// bid = (qt*4 + h_in)*8 + g, g = b*4+kvh: combine blocks land on the XCD whose L2
// holds the split partials they read. Thread t: row r=t>>2 (64 rows), quad q=t&3.
__global__ __launch_bounds__(256) void attn_combine_k(
    const float* __restrict__ pO, const float* __restrict__ pML,
    const float* __restrict__ g1t, const float* __restrict__ lng,
    const float* __restrict__ lnb, bf16* __restrict__ aout) {
  const int bid = blockIdx.x;
  const int g = bid & 7, j = bid >> 3;
  const int h_in = j & 3, qt = j >> 2;
  const int b = g >> 2, kvh = g & 3, h = kvh * 4 + h_in;
  const int t = threadIdx.x, r = t >> 2, q = t & 3;
  const int nsplit = (qt + 8) >> 3;  // ceil((qt+1)/8)
  int base;
  if (qt >= 24) base = (31 - qt) * 4;
  else if (qt >= 16) base = 32 + (23 - qt) * 3;
  else if (qt >= 8) base = 56 + (15 - qt) * 2;
  else base = 72 + (7 - qt);

  float m[4] = {-1e30f, -1e30f, -1e30f, -1e30f};
  float l[4] = {0.f, 0.f, 0.f, 0.f};
  float mstar = -1e30f;
#pragma unroll
  for (int s = 0; s < 4; s++)
    if (s < nsplit) {
      int pb = ((base + s) * 4 + h_in) * 8 + g;
      m[s] = pML[(size_t)pb * 128 + r * 2];
      l[s] = pML[(size_t)pb * 128 + r * 2 + 1];
      mstar = fmaxf(mstar, m[s]);
    }
  float w[4] = {0.f, 0.f, 0.f, 0.f};
  float L = 0.f;
#pragma unroll
  for (int s = 0; s < 4; s++)
    if (s < nsplit) { w[s] = __expf(m[s] - mstar); L += w[s] * l[s]; }
  const float invL = 1.f / L;

  float ov[32];
  float sum = 0.f, sq = 0.f;
#pragma unroll
  for (int jj8 = 0; jj8 < 8; jj8++) {
    int d = q * 32 + jj8 * 4;
    float4 a = {0.f, 0.f, 0.f, 0.f};
#pragma unroll
    for (int s = 0; s < 4; s++)
      if (s < nsplit) {
        int pb = ((base + s) * 4 + h_in) * 8 + g;
        float4 o = *(const float4*)&pO[(size_t)pb * 8192 + r * 128 + d];
        a.x += w[s] * o.x; a.y += w[s] * o.y; a.z += w[s] * o.z; a.w += w[s] * o.w;
      }
    a.x *= invL; a.y *= invL; a.z *= invL; a.w *= invL;
    ov[jj8 * 4] = a.x; ov[jj8 * 4 + 1] = a.y; ov[jj8 * 4 + 2] = a.z; ov[jj8 * 4 + 3] = a.w;
    sum += a.x + a.y + a.z + a.w;
    sq += a.x * a.x + a.y * a.y + a.z * a.z + a.w * a.w;
  }
  sum += __shfl_xor(sum, 1); sum += __shfl_xor(sum, 2);
  sq  += __shfl_xor(sq, 1);  sq  += __shfl_xor(sq, 2);
  const float mu = sum * (1.f / 128.f);
  const float var = sq * (1.f / 128.f) - mu * mu;
  const float rstd = rsqrtf(var + 1e-5f);

  const int qrow = qt * 64 + r;
  const size_t tok = (size_t)b * 2048 + qrow;
  const float gg = g1t[(size_t)h * 4096 + tok];
  bf16* og = aout + tok * 2048 + h * 128 + q * 32;
#pragma unroll
  for (int j8 = 0; j8 < 4; j8++) {
    bf16x8 o8;
#pragma unroll
    for (int jj = 0; jj < 8; jj++) {
      int d = q * 32 + j8 * 8 + jj;
      float v = (ov[j8 * 8 + jj] - mu) * rstd * lng[d] + lnb[d];
      ((bf16*)&o8)[jj] = tobf(v * gg);
    }
    *(bf16x8*)(og + j8 * 8) = o8;
  }
}

// ---------------- launch ----------------
extern "C" void kernel_launch(void* const* d_in, const int* in_sizes, int n_in,
                              void* d_out, int out_size, void* d_ws, size_t ws_size,
                              hipStream_t stream) {
  (void)in_sizes; (void)n_in; (void)out_size; (void)ws_size;
  const float* X   = (const float*)d_in[0];
  const int*   pos = (const int*)d_in[1];
  const float* Wq  = (const float*)d_in[2];
  const float* Wk  = (const float*)d_in[3];
  const float* Wv  = (const float*)d_in[4];
  const float* Wo  = (const float*)d_in[5];
  const float* Wg1 = (const float*)d_in[6];
  const float* bg1 = (const float*)d_in[7];
  const float* Wg2 = (const float*)d_in[8];
  const float* bg2 = (const float*)d_in[9];
  const float* lng = (const float*)d_in[10];
  const float* lnb = (const float*)d_in[11];

  char* ws = (char*)d_ws;
  size_t off = 0;
  auto alloc = [&](size_t bytes) {
    void* p = ws + off;
    off += (bytes + 255) & ~(size_t)255;
    return p;
  };
  bf16*  WT   = (bf16*)alloc(3200ull * 2048 * 2);   // [Wq^T; Wk^T; Wv^T; Wg1^T; Wg2^T; pad]
  bf16*  WoT  = (bf16*)alloc(2048ull * 2048 * 2);
  bf16*  Xbf  = (bf16*)alloc(4096ull * 2048 * 2);
  bf16*  qkv  = (bf16*)alloc(4096ull * 3072 * 2);
  bf16*  attn = (bf16*)alloc(4096ull * 2048 * 2);
  float* cosT = (float*)alloc(2048ull * 64 * 4);
  float* sinT = (float*)alloc(2048ull * 64 * 4);
  float* g1t  = (float*)alloc(16ull * 4096 * 4);    // [head][token]
  float* g2t  = (float*)alloc(16ull * 4096 * 4);
  float* pO   = (float*)alloc(2560ull * 8192 * 4);  // split partial O (raw)
  float* pML  = (float*)alloc(2560ull * 128 * 4);   // split partial m,l

  dim3 tb(32, 8);
  transpose_cast_k<<<dim3(64, 64), tb, 0, stream>>>(Wq, WT, 2048, 2048);
  transpose_cast_k<<<dim3(64, 16), tb, 0, stream>>>(Wk, WT + 2048ull * 2048, 2048, 512);
  transpose_cast_k<<<dim3(64, 16), tb, 0, stream>>>(Wv, WT + 2560ull * 2048, 2048, 512);
  transpose_cast_k<<<dim3(64, 64), tb, 0, stream>>>(Wo, WoT, 2048, 2048);
  gw_transpose_k<<<32, 256, 0, stream>>>(Wg1, Wg2, WT);
  cast_x_k<<<8192, 256, 0, stream>>>(X, Xbf);
  rope_table_k<<<2048, 64, 0, stream>>>(pos, cosT, sinT);

  // [qkv | g1t | g2t] = Xbf @ WT^T  (4096 x 3200)
  gemm_qkv_k<<<dim3(25, 32), 256, 0, stream>>>(Xbf, WT, qkv, g1t, g2t, bg1, bg2);
  rope_apply_k<<<2560, 256, 0, stream>>>(qkv, cosT, sinT);
  attn_split_k<<<2560, 256, 0, stream>>>(qkv, g2t, pO, pML);
  attn_combine_k<<<1024, 256, 0, stream>>>(pO, pML, g1t, lng, lnb, attn);
  // out = attn @ Wo  (4096 x 2048), fp32
  gemm_out_k<<<dim3(16, 32), 256, 0, stream>>>(attn, WoT, (float*)d_out, 4096, 2048, 2048);
}

// Round 7
// 296.405 us; speedup vs baseline: 1.5579x; 1.5085x over previous
//
#include <hip/hip_runtime.h>
#include <hip/hip_bf16.h>
#include <stdint.h>
#include <string.h>

using bf16 = __hip_bfloat16;
typedef __attribute__((ext_vector_type(8))) short bf16x8;   // 8 bf16 (4 VGPRs) MFMA A/B frag
typedef __attribute__((ext_vector_type(4))) float f32x4;    // MFMA C/D frag

#define DEV static __device__ __forceinline__

DEV bf16 tobf(float f) { return __float2bfloat16(f); }
DEV float tof(bf16 h) { return __bfloat162float(h); }

// async global->LDS, 16B per lane. LDS dest semantics: wave-uniform base + lane*16.
DEV void gload_lds16(const void* g, void* l) {
  __builtin_amdgcn_global_load_lds((__attribute__((address_space(1))) void*)g,
                                   (__attribute__((address_space(3))) void*)l,
                                   16, 0, 0);
}

// ---------------- prep kernels ----------------

// dst[n][k] = (bf16)src[k][n]; src is K x N row-major. block (32,8), grid (K/32, N/32)
__global__ void transpose_cast_k(const float* __restrict__ src, bf16* __restrict__ dst,
                                 int K, int N) {
  __shared__ float tile[32][33];
  int kb = blockIdx.x * 32, nb = blockIdx.y * 32;
  int tx = threadIdx.x, ty = threadIdx.y;
#pragma unroll
  for (int i = 0; i < 32; i += 8)
    tile[ty + i][tx] = src[(size_t)(kb + ty + i) * N + nb + tx];
  __syncthreads();
#pragma unroll
  for (int i = 0; i < 32; i += 8)
    dst[(size_t)(nb + ty + i) * K + kb + tx] = tobf(tile[tx][ty + i]);
}

// Wg (2048x16) -> WT rows: dst[r][k] = Wg[k][r]. grid 32 blocks: g=bx>>4, r=bx&15.
__global__ void gw_transpose_k(const float* __restrict__ Wg1, const float* __restrict__ Wg2,
                               bf16* __restrict__ dstbase) {
  int g = blockIdx.x >> 4, r = blockIdx.x & 15;
  const float* src = g ? Wg2 : Wg1;
  bf16* dst = dstbase + (size_t)(3072 + g * 16 + r) * 2048;
  for (int k = threadIdx.x; k < 2048; k += 256) dst[k] = tobf(src[(size_t)k * 16 + r]);
}

__global__ void cast_x_k(const float* __restrict__ src, bf16* __restrict__ dst) {
  int i = blockIdx.x * blockDim.x + threadIdx.x;  // one float4 per thread
  float4 v = ((const float4*)src)[i];
  bf16 t[4] = {tobf(v.x), tobf(v.y), tobf(v.z), tobf(v.w)};
  uint2 p; __builtin_memcpy(&p, t, 8);
  ((uint2*)dst)[i] = p;
}

// cos/sin tables: [S][64]. grid S blocks x 64 threads.
__global__ void rope_table_k(const int* __restrict__ pos, float* __restrict__ cosT,
                             float* __restrict__ sinT) {
  int s = blockIdx.x, i = threadIdx.x;
  double inv = exp(-((double)(2 * i) / 128.0) * log(10000.0));
  float f = (float)pos[s] * (float)inv;
  cosT[s * 64 + i] = cosf(f);
  sinT[s * 64 + i] = sinf(f);
}

// RoPE in place on qkv, vectorized 16B: thread = (token t, head 0..19, chunk c of 8 dims).
__global__ __launch_bounds__(256) void rope_apply_k(
    bf16* __restrict__ qkv, const float* __restrict__ cosT, const float* __restrict__ sinT) {
  int idx = blockIdx.x * 256 + threadIdx.x;  // 4096*20*8 = 655360
  int c = idx & 7, hh = idx >> 3;
  int head = hh % 20, t = hh / 20;
  int s = t & 2047;
  size_t base = (size_t)t * 3072 + (head < 16 ? head * 128 : 2048 + (head - 16) * 128);
  int d0 = c * 8;
  bf16x8 lo = *(const bf16x8*)(qkv + base + d0);
  bf16x8 hi = *(const bf16x8*)(qkv + base + d0 + 64);
  float4 c0 = *(const float4*)(cosT + s * 64 + d0);
  float4 c1 = *(const float4*)(cosT + s * 64 + d0 + 4);
  float4 s0 = *(const float4*)(sinT + s * 64 + d0);
  float4 s1 = *(const float4*)(sinT + s * 64 + d0 + 4);
  float cs[8] = {c0.x, c0.y, c0.z, c0.w, c1.x, c1.y, c1.z, c1.w};
  float sn[8] = {s0.x, s0.y, s0.z, s0.w, s1.x, s1.y, s1.z, s1.w};
  bf16x8 olo, ohi;
#pragma unroll
  for (int j = 0; j < 8; j++) {
    float a = tof(((const bf16*)&lo)[j]), b = tof(((const bf16*)&hi)[j]);
    ((bf16*)&olo)[j] = tobf(a * cs[j] - b * sn[j]);
    ((bf16*)&ohi)[j] = tobf(b * cs[j] + a * sn[j]);
  }
  *(bf16x8*)(qkv + base + d0) = olo;
  *(bf16x8*)(qkv + base + d0 + 64) = ohi;
}

// ---------------- QKV+gates GEMM: [qkv | g1t | g2t] = Xbf @ WT^T ----------------
// Gates written TRANSPOSED: g1t/g2t are [16][4096] fp32 (head-major).
__global__ __launch_bounds__(256, 2) void gemm_qkv_k(
    const bf16* __restrict__ A, const bf16* __restrict__ Bt, bf16* __restrict__ qkv,
    float* __restrict__ g1t, float* __restrict__ g2t,
    const float* __restrict__ bg1, const float* __restrict__ bg2) {
  constexpr int BK = 32, K = 2048;
  __shared__ bf16 sA[2][128 * BK];
  __shared__ bf16 sB[2][128 * BK];
  const int tid = threadIdx.x, wave = tid >> 6, lane = tid & 63;
  const int lhi = lane >> 4, llo = lane & 15;
  const int wm = wave >> 1, wn = wave & 1;
  const int bm = blockIdx.y, bn = blockIdx.x;
  const bf16* Ag = A + (size_t)bm * 128 * K;
  const bf16* Bg = Bt + (size_t)bn * 128 * K;

  f32x4 acc[4][4];
#pragma unroll
  for (int m = 0; m < 4; m++)
#pragma unroll
    for (int n = 0; n < 4; n++) acc[m][n] = f32x4{0.f, 0.f, 0.f, 0.f};

  auto stage = [&](int buf, int kt) {
#pragma unroll
    for (int i = 0; i < 2; i++) {
      int c = i * 256 + tid, row = c >> 2, c8 = c & 3;
      gload_lds16(Ag + (size_t)row * K + kt * BK + c8 * 8, &sA[buf][c * 8]);
    }
#pragma unroll
    for (int i = 0; i < 2; i++) {
      int c = i * 256 + tid, row = c >> 2, c8 = c & 3;
      gload_lds16(Bg + (size_t)row * K + kt * BK + c8 * 8, &sB[buf][c * 8]);
    }
  };

  const int NT = K / BK;
  stage(0, 0);
  for (int kt = 0; kt < NT; kt++) {
    __syncthreads();
    if (kt + 1 < NT) stage((kt + 1) & 1, kt + 1);
    const bf16* a_ = sA[kt & 1];
    const bf16* b_ = sB[kt & 1];
    bf16x8 af[4], bfr[4];
#pragma unroll
    for (int m = 0; m < 4; m++)
      af[m] = *(const bf16x8*)&a_[(wm * 64 + m * 16 + llo) * BK + lhi * 8];
#pragma unroll
    for (int n = 0; n < 4; n++)
      bfr[n] = *(const bf16x8*)&b_[(wn * 64 + n * 16 + llo) * BK + lhi * 8];
#pragma unroll
    for (int m = 0; m < 4; m++)
#pragma unroll
      for (int n = 0; n < 4; n++)
        acc[m][n] = __builtin_amdgcn_mfma_f32_16x16x32_bf16(af[m], bfr[n], acc[m][n], 0, 0, 0);
  }

  const int r0 = bm * 128 + wm * 64, c0 = bn * 128 + wn * 64;
#pragma unroll
  for (int m = 0; m < 4; m++)
#pragma unroll
    for (int n = 0; n < 4; n++) {
      int col = c0 + n * 16 + llo;
#pragma unroll
      for (int r = 0; r < 4; r++) {
        int row = r0 + m * 16 + lhi * 4 + r;
        if (col < 3072) {
          qkv[(size_t)row * 3072 + col] = tobf(acc[m][n][r]);
        } else if (col < 3104) {
          int idx = col - 3072, hh = idx & 15;
          float b = (idx < 16) ? bg1[hh] : bg2[hh];
          float v = 1.f / (1.f + __expf(-(acc[m][n][r] + b)));
          ((idx < 16) ? g1t : g2t)[(size_t)hh * 4096 + row] = v;
        }
      }
    }
}

// ---------------- generic GEMM: C = A(MxK) * Bt(NxK)^T, fp32 out ----------------
__global__ __launch_bounds__(256, 2) void gemm_out_k(
    const bf16* __restrict__ A, const bf16* __restrict__ Bt, float* __restrict__ C,
    int M, int N, int K) {
  constexpr int BK = 32;
  __shared__ bf16 sA[2][128 * BK];
  __shared__ bf16 sB[2][128 * BK];
  const int tid = threadIdx.x, wave = tid >> 6, lane = tid & 63;
  const int lhi = lane >> 4, llo = lane & 15;
  const int wm = wave >> 1, wn = wave & 1;
  const int bm = blockIdx.y, bn = blockIdx.x;
  const bf16* Ag = A + (size_t)bm * 128 * K;
  const bf16* Bg = Bt + (size_t)bn * 128 * K;

  f32x4 acc[4][4];
#pragma unroll
  for (int m = 0; m < 4; m++)
#pragma unroll
    for (int n = 0; n < 4; n++) acc[m][n] = f32x4{0.f, 0.f, 0.f, 0.f};

  auto stage = [&](int buf, int kt) {
#pragma unroll
    for (int i = 0; i < 2; i++) {
      int c = i * 256 + tid, row = c >> 2, c8 = c & 3;
      gload_lds16(Ag + (size_t)row * K + kt * BK + c8 * 8, &sA[buf][c * 8]);
    }
#pragma unroll
    for (int i = 0; i < 2; i++) {
      int c = i * 256 + tid, row = c >> 2, c8 = c & 3;
      gload_lds16(Bg + (size_t)row * K + kt * BK + c8 * 8, &sB[buf][c * 8]);
    }
  };

  const int NT = K / BK;
  stage(0, 0);
  for (int kt = 0; kt < NT; kt++) {
    __syncthreads();
    if (kt + 1 < NT) stage((kt + 1) & 1, kt + 1);
    const bf16* a_ = sA[kt & 1];
    const bf16* b_ = sB[kt & 1];
    bf16x8 af[4], bfr[4];
#pragma unroll
    for (int m = 0; m < 4; m++)
      af[m] = *(const bf16x8*)&a_[(wm * 64 + m * 16 + llo) * BK + lhi * 8];
#pragma unroll
    for (int n = 0; n < 4; n++)
      bfr[n] = *(const bf16x8*)&b_[(wn * 64 + n * 16 + llo) * BK + lhi * 8];
#pragma unroll
    for (int m = 0; m < 4; m++)
#pragma unroll
      for (int n = 0; n < 4; n++)
        acc[m][n] = __builtin_amdgcn_mfma_f32_16x16x32_bf16(af[m], bfr[n], acc[m][n], 0, 0, 0);
  }

  const int r0 = bm * 128 + wm * 64, c0 = bn * 128 + wn * 64;
#pragma unroll
  for (int m = 0; m < 4; m++)
#pragma unroll
    for (int n = 0; n < 4; n++)
#pragma unroll
      for (int r = 0; r < 4; r++)
        C[(size_t)(r0 + m * 16 + lhi * 4 + r) * N + (c0 + n * 16 + llo)] = acc[m][n][r];
}

// ---------------- shared attention epilogue: LN + g1 gate + coalesced store ----------------
// o[dt][r] = normalized O (already / L) for row wave*16+lhi*4+r, col dt*16+llo.
// Uses sK (64x128 bf16) as staging; callers must call under uniform control flow.
DEV void finalize_store(const f32x4 (&o)[8], int wave, int lhi, int llo, int tid,
                        int h, int qt, size_t tok0,
                        const float* __restrict__ g1t, const float* __restrict__ lng,
                        const float* __restrict__ lnb, bf16* sK, bf16* __restrict__ aout) {
  float sum[4] = {0, 0, 0, 0}, sq[4] = {0, 0, 0, 0};
#pragma unroll
  for (int dt = 0; dt < 8; dt++)
#pragma unroll
    for (int r = 0; r < 4; r++) {
      float v = o[dt][r];
      sum[r] += v;
      sq[r] += v * v;
    }
  float mu[4], rstd[4];
#pragma unroll
  for (int r = 0; r < 4; r++) {
    float s1 = sum[r], s2 = sq[r];
    s1 += __shfl_xor(s1, 1); s1 += __shfl_xor(s1, 2); s1 += __shfl_xor(s1, 4); s1 += __shfl_xor(s1, 8);
    s2 += __shfl_xor(s2, 1); s2 += __shfl_xor(s2, 2); s2 += __shfl_xor(s2, 4); s2 += __shfl_xor(s2, 8);
    float m_ = s1 * (1.f / 128.f);
    float var = s2 * (1.f / 128.f) - m_ * m_;
    mu[r] = m_;
    rstd[r] = rsqrtf(var + 1e-5f);
  }
  __syncthreads();  // prior users of sK done
#pragma unroll
  for (int r = 0; r < 4; r++) {
    int lrow = wave * 16 + lhi * 4 + r;
    float gg = g1t[(size_t)h * 4096 + tok0 + qt * 64 + lrow];
#pragma unroll
    for (int dt = 0; dt < 8; dt++) {
      int d = dt * 16 + llo;
      float v = (o[dt][r] - mu[r]) * rstd[r] * lng[d] + lnb[d];
      sK[lrow * 128 + d] = tobf(v * gg);
    }
  }
  __syncthreads();
#pragma unroll
  for (int i = 0; i < 4; i++) {
    int c = i * 256 + tid, lr = c >> 4, c8 = c & 15;
    *(uint4*)(aout + (tok0 + qt * 64 + lr) * 2048 + h * 128 + c8 * 8) =
        *(const uint4*)&sK[lr * 128 + c8 * 8];
  }
}

// ---------------- split-K causal GQA attention: 2 q-heads per block ----------------
// 768 blocks = 48 LPT-ordered units x 2 head-pairs x 8 XCD groups. bid=(u*2+hp)*8+g,
// g=b*4+kvh keeps each (b,kvh) group's K/V on one XCD's L2. Units (len descending):
//   u<16       : qt=16+u,   split0, tiles [0,16)          (partial)
//   u>=16 even : qt=15-p,   single, tiles [0,qt+1)        (direct finalize)
//   u>=16 odd  : qt=31-p,   split1, tiles [16,qt+1)       (partial)   [p=(u-16)>>1]
// Both heads (h0=kvh*4+hp*2, h0+1) share staged K/V and the V fragments in PV.
// Partials: pO [combo][sub][wave][dt][lane] as f32x4 (1KB/wave contiguous stores);
// combo=(qt-16)*2+s, sub=((g*2+hp)*2+hh).
__global__ __launch_bounds__(256, 2) void attn_split_k(
    const bf16* __restrict__ qkv, const float* __restrict__ g2t,
    const float* __restrict__ g1t, const float* __restrict__ lng,
    const float* __restrict__ lnb,
    float* __restrict__ pO, float* __restrict__ pML, bf16* __restrict__ aout) {
  constexpr int S = 2048, LD = 3072;
  const int bid = blockIdx.x;
  const int g = bid & 7, j = bid >> 3;
  const int hp = j & 1, u = j >> 1;
  int qt, k0, s;
  bool partial;
  if (u < 16) { qt = 16 + u; k0 = 0; s = 0; partial = true; }
  else {
    int p = (u - 16) >> 1;
    if (((u - 16) & 1) == 0) { qt = 15 - p; k0 = 0; s = 0; partial = false; }
    else { qt = 31 - p; k0 = 16; s = 1; partial = true; }
  }
  const int k1 = (u < 16) ? 16 : qt + 1;

  const int b = g >> 2, kvh = g & 3, h0 = kvh * 4 + hp * 2;
  const int tid = threadIdx.x, wave = tid >> 6, lane = tid & 63;
  const int lhi = lane >> 4, llo = lane & 15;
  const size_t tok0 = (size_t)b * S;

  __shared__ bf16 sK[64 * 128];      // [kv][d], XOR-swizzled ((row&7)<<3 on element idx)
  __shared__ bf16 sV[128 * 64];      // [d][kv] transposed, XOR-swizzled ((d&7)<<3)
  __shared__ bf16 sP[4][2][16][72];  // per-wave, per-head P tile, padded

  const int qrow0 = qt * 64 + wave * 16;

  bf16x8 qf[2][4];
#pragma unroll
  for (int hh = 0; hh < 2; hh++) {
    const bf16* qg = qkv + (tok0 + qrow0 + llo) * LD + (h0 + hh) * 128;
#pragma unroll
    for (int dc = 0; dc < 4; dc++) qf[hh][dc] = *(const bf16x8*)(qg + dc * 32 + lhi * 8);
  }

  f32x4 oacc[2][8];
#pragma unroll
  for (int hh = 0; hh < 2; hh++)
#pragma unroll
    for (int i = 0; i < 8; i++) oacc[hh][i] = f32x4{0.f, 0.f, 0.f, 0.f};
  float mrow[2][4], lrow[2][4];
#pragma unroll
  for (int hh = 0; hh < 2; hh++)
#pragma unroll
    for (int r = 0; r < 4; r++) { mrow[hh][r] = -1e30f; lrow[hh][r] = 0.f; }
  const float scale = 0.08838834764831845f;  // 1/sqrt(128)

  uint4 kreg[4];
  bf16x8 vreg[4];
  float gvreg[2];
  const int vdg = tid >> 4;   // d-group: 8 d elems
  const int vkg = tid & 15;   // kv-group: 4 kv rows

  auto issue_loads = [&](int kt) {
#pragma unroll
    for (int i = 0; i < 4; i++) {
      int c = i * 256 + tid, row = c >> 4, c8 = c & 15;
      kreg[i] = *(const uint4*)(qkv + (tok0 + kt * 64 + row) * LD + 2048 + kvh * 128 + c8 * 8);
    }
#pragma unroll
    for (int r = 0; r < 4; r++)
      vreg[r] = *(const bf16x8*)(qkv + (tok0 + kt * 64 + vkg * 4 + r) * LD + 2560 +
                                 kvh * 128 + vdg * 8);
#pragma unroll
    for (int hh = 0; hh < 2; hh++)
      gvreg[hh] = g2t[(size_t)(h0 + hh) * 4096 + tok0 + kt * 64 + lane];
  };

  auto write_lds = [&]() {
#pragma unroll
    for (int i = 0; i < 4; i++) {
      int c = i * 256 + tid, row = c >> 4, c8 = c & 15;
      int eidx = (row * 128 + c8 * 8) ^ ((row & 7) << 3);
      *(uint4*)&sK[eidx] = kreg[i];
    }
#pragma unroll
    for (int e = 0; e < 8; e++) {
      int d = vdg * 8 + e;          // d & 7 == e
      uint32_t lo = (uint32_t)(unsigned short)vreg[0][e] |
                    ((uint32_t)(unsigned short)vreg[1][e] << 16);
      uint32_t hi = (uint32_t)(unsigned short)vreg[2][e] |
                    ((uint32_t)(unsigned short)vreg[3][e] << 16);
      int eidx = (d * 64 + vkg * 4) ^ (e << 3);
      uint2 pk; pk.x = lo; pk.y = hi;
      *(uint2*)&sV[eidx] = pk;
    }
  };

  issue_loads(k0);
  for (int kt = k0; kt < k1; kt++) {
    __syncthreads();  // previous tile's LDS reads complete before overwrite
    write_lds();      // vmcnt wait lands here (data long arrived)
    float gv0 = gvreg[0], gv1 = gvreg[1];
    __syncthreads();  // LDS writes visible
    if (kt + 1 < k1) issue_loads(kt + 1);  // in flight during compute (T14)

    const bool diag = (kt == qt);
#pragma unroll
    for (int hh = 0; hh < 2; hh++) {
      // ---- QK^T ----
      f32x4 sc[4];
#pragma unroll
      for (int ct = 0; ct < 4; ct++) {
        f32x4 acc = f32x4{0.f, 0.f, 0.f, 0.f};
#pragma unroll
        for (int dc = 0; dc < 4; dc++) {
          int row = ct * 16 + llo;
          bf16x8 kf = *(const bf16x8*)&sK[(row * 128 + dc * 32 + lhi * 8) ^ ((row & 7) << 3)];
          acc = __builtin_amdgcn_mfma_f32_16x16x32_bf16(qf[hh][dc], kf, acc, 0, 0, 0);
        }
        sc[ct] = acc;
      }
      // ---- scale + causal mask + online softmax (exact defer-max) ----
      float pm[4] = {-1e30f, -1e30f, -1e30f, -1e30f};
#pragma unroll
      for (int ct = 0; ct < 4; ct++) {
        int kv = kt * 64 + ct * 16 + llo;
#pragma unroll
        for (int r = 0; r < 4; r++) {
          float s_ = sc[ct][r] * scale;
          if (diag && kv > qrow0 + lhi * 4 + r) s_ = -1e30f;
          sc[ct][r] = s_;
          pm[r] = fmaxf(pm[r], s_);
        }
      }
#pragma unroll
      for (int r = 0; r < 4; r++) {
        float v = pm[r];
        v = fmaxf(v, __shfl_xor(v, 1));
        v = fmaxf(v, __shfl_xor(v, 2));
        v = fmaxf(v, __shfl_xor(v, 4));
        v = fmaxf(v, __shfl_xor(v, 8));
        pm[r] = v;
      }
      int need = 0;
#pragma unroll
      for (int r = 0; r < 4; r++) need |= (pm[r] > mrow[hh][r]) ? 1 : 0;
      if (__any(need)) {
#pragma unroll
        for (int r = 0; r < 4; r++) {
          float mnew = fmaxf(mrow[hh][r], pm[r]);
          float al = __expf(mrow[hh][r] - mnew);
          mrow[hh][r] = mnew;
          lrow[hh][r] *= al;
#pragma unroll
          for (int i = 0; i < 8; i++) oacc[hh][i][r] *= al;
        }
      }
      float gv = hh ? gv1 : gv0;
      float g2v[4];
#pragma unroll
      for (int ct = 0; ct < 4; ct++) g2v[ct] = __shfl(gv, ct * 16 + llo);
      float rs[4] = {0.f, 0.f, 0.f, 0.f};
#pragma unroll
      for (int ct = 0; ct < 4; ct++) {
#pragma unroll
        for (int r = 0; r < 4; r++) {
          float p = __expf(sc[ct][r] - mrow[hh][r]);
          rs[r] += p;  // softmax denom uses UNGATED p
          sP[wave][hh][lhi * 4 + r][ct * 16 + llo] = tobf(p * g2v[ct]);
        }
      }
#pragma unroll
      for (int r = 0; r < 4; r++) {
        float v = rs[r];
        v += __shfl_xor(v, 1); v += __shfl_xor(v, 2); v += __shfl_xor(v, 4); v += __shfl_xor(v, 8);
        lrow[hh][r] += v;
      }
    }
    // ---- PV: both heads share each V fragment ----
#pragma unroll
    for (int kc = 0; kc < 2; kc++) {
      bf16x8 pf0 = *(const bf16x8*)&sP[wave][0][llo][kc * 32 + lhi * 8];
      bf16x8 pf1 = *(const bf16x8*)&sP[wave][1][llo][kc * 32 + lhi * 8];
#pragma unroll
      for (int dt = 0; dt < 8; dt++) {
        int d = dt * 16 + llo;
        bf16x8 vf = *(const bf16x8*)&sV[(d * 64 + kc * 32 + lhi * 8) ^ ((d & 7) << 3)];
        oacc[0][dt] = __builtin_amdgcn_mfma_f32_16x16x32_bf16(pf0, vf, oacc[0][dt], 0, 0, 0);
        oacc[1][dt] = __builtin_amdgcn_mfma_f32_16x16x32_bf16(pf1, vf, oacc[1][dt], 0, 0, 0);
      }
    }
  }

  if (partial) {
    const int combo = (qt - 16) * 2 + s;
#pragma unroll
    for (int hh = 0; hh < 2; hh++) {
      const int sub = (g * 2 + hp) * 2 + hh;
      f32x4* dst = (f32x4*)pO + (size_t)(combo * 32 + sub) * 2048;
#pragma unroll
      for (int dt = 0; dt < 8; dt++)
        dst[(wave * 8 + dt) * 64 + lane] = oacc[hh][dt];
      if (llo == 0) {
#pragma unroll
        for (int r = 0; r < 4; r++) {
          int row = wave * 16 + lhi * 4 + r;
          float* pm = pML + ((size_t)(combo * 32 + sub) * 64 + row) * 2;
          pm[0] = mrow[hh][r];
          pm[1] = lrow[hh][r];
        }
      }
    }
  } else {
#pragma unroll
    for (int hh = 0; hh < 2; hh++) {
      float inv[4];
#pragma unroll
      for (int r = 0; r < 4; r++) inv[r] = 1.f / lrow[hh][r];
      f32x4 o[8];
#pragma unroll
      for (int dt = 0; dt < 8; dt++)
#pragma unroll
        for (int r = 0; r < 4; r++) o[dt][r] = oacc[hh][dt][r] * inv[r];
      finalize_store(o, wave, lhi, llo, tid, h0 + hh, qt, tok0, g1t, lng, lnb, sK, aout);
    }
  }
}

// ---------------- combine 2 partials + LN + g1 gate ----------------
// 256 blocks = 16 qt16 x 2 hp x 8 g; mirrors the split's register layout so pO reads
// are the same coalesced f32x4 pattern. Handles qt>=16 rows only.
__global__ __launch_bounds__(256) void attn_combine_k(
    const float* __restrict__ pO, const float* __restrict__ pML,
    const float* __restrict__ g1t, const float* __restrict__ lng,
    const float* __restrict__ lnb, bf16* __restrict__ aout) {
  __shared__ bf16 sK[64 * 128];
  const int bid = blockIdx.x;
  const int g = bid & 7, j = bid >> 3;
  const int hp = j & 1, qt16 = j >> 1;
  const int qt = 16 + qt16;
  const int b = g >> 2, kvh = g & 3, h0 = kvh * 4 + hp * 2;
  const int tid = threadIdx.x, wave = tid >> 6, lane = tid & 63;
  const int lhi = lane >> 4, llo = lane & 15;
  const size_t tok0 = (size_t)b * 2048;
  const int c0 = qt16 * 2, c1 = qt16 * 2 + 1;
#pragma unroll
  for (int hh = 0; hh < 2; hh++) {
    const int sub = (g * 2 + hp) * 2 + hh;
    const f32x4* p0 = (const f32x4*)pO + (size_t)(c0 * 32 + sub) * 2048;
    const f32x4* p1 = (const f32x4*)pO + (size_t)(c1 * 32 + sub) * 2048;
    float w0[4], w1[4], inv[4];
#pragma unroll
    for (int r = 0; r < 4; r++) {
      int row = wave * 16 + lhi * 4 + r;
      const float* q0 = pML + ((size_t)(c0 * 32 + sub) * 64 + row) * 2;
      const float* q1 = pML + ((size_t)(c1 * 32 + sub) * 64 + row) * 2;
      float m0 = q0[0], l0 = q0[1], m1 = q1[0], l1 = q1[1];
      float ms = fmaxf(m0, m1);
      w0[r] = __expf(m0 - ms);
      w1[r] = __expf(m1 - ms);
      inv[r] = 1.f / (w0[r] * l0 + w1[r] * l1);
    }
    f32x4 o[8];
#pragma unroll
    for (int dt = 0; dt < 8; dt++) {
      f32x4 a = p0[(wave * 8 + dt) * 64 + lane];
      f32x4 c = p1[(wave * 8 + dt) * 64 + lane];
#pragma unroll
      for (int r = 0; r < 4; r++) o[dt][r] = (w0[r] * a[r] + w1[r] * c[r]) * inv[r];
    }
    finalize_store(o, wave, lhi, llo, tid, h0 + hh, qt, tok0, g1t, lng, lnb, sK, aout);
  }
}

// ---------------- launch ----------------
extern "C" void kernel_launch(void* const* d_in, const int* in_sizes, int n_in,
                              void* d_out, int out_size, void* d_ws, size_t ws_size,
                              hipStream_t stream) {
  (void)in_sizes; (void)n_in; (void)out_size; (void)ws_size;
  const float* X   = (const float*)d_in[0];
  const int*   pos = (const int*)d_in[1];
  const float* Wq  = (const float*)d_in[2];
  const float* Wk  = (const float*)d_in[3];
  const float* Wv  = (const float*)d_in[4];
  const float* Wo  = (const float*)d_in[5];
  const float* Wg1 = (const float*)d_in[6];
  const float* bg1 = (const float*)d_in[7];
  const float* Wg2 = (const float*)d_in[8];
  const float* bg2 = (const float*)d_in[9];
  const float* lng = (const float*)d_in[10];
  const float* lnb = (const float*)d_in[11];

  char* ws = (char*)d_ws;
  size_t off = 0;
  auto alloc = [&](size_t bytes) {
    void* p = ws + off;
    off += (bytes + 255) & ~(size_t)255;
    return p;
  };
  bf16*  WT   = (bf16*)alloc(3200ull * 2048 * 2);   // [Wq^T; Wk^T; Wv^T; Wg1^T; Wg2^T; pad]
  bf16*  WoT  = (bf16*)alloc(2048ull * 2048 * 2);
  bf16*  Xbf  = (bf16*)alloc(4096ull * 2048 * 2);
  bf16*  qkv  = (bf16*)alloc(4096ull * 3072 * 2);
  bf16*  attn = (bf16*)alloc(4096ull * 2048 * 2);
  float* cosT = (float*)alloc(2048ull * 64 * 4);
  float* sinT = (float*)alloc(2048ull * 64 * 4);
  float* g1t  = (float*)alloc(16ull * 4096 * 4);    // [head][token]
  float* g2t  = (float*)alloc(16ull * 4096 * 4);
  float* pO   = (float*)alloc(32ull * 32 * 8192 * 4);  // [combo][sub] f32x4-coalesced partial O
  float* pML  = (float*)alloc(32ull * 32 * 64 * 2 * 4);

  dim3 tb(32, 8);
  transpose_cast_k<<<dim3(64, 64), tb, 0, stream>>>(Wq, WT, 2048, 2048);
  transpose_cast_k<<<dim3(64, 16), tb, 0, stream>>>(Wk, WT + 2048ull * 2048, 2048, 512);
  transpose_cast_k<<<dim3(64, 16), tb, 0, stream>>>(Wv, WT + 2560ull * 2048, 2048, 512);
  transpose_cast_k<<<dim3(64, 64), tb, 0, stream>>>(Wo, WoT, 2048, 2048);
  gw_transpose_k<<<32, 256, 0, stream>>>(Wg1, Wg2, WT);
  cast_x_k<<<8192, 256, 0, stream>>>(X, Xbf);
  rope_table_k<<<2048, 64, 0, stream>>>(pos, cosT, sinT);

  // [qkv | g1t | g2t] = Xbf @ WT^T  (4096 x 3200)
  gemm_qkv_k<<<dim3(25, 32), 256, 0, stream>>>(Xbf, WT, qkv, g1t, g2t, bg1, bg2);
  rope_apply_k<<<2560, 256, 0, stream>>>(qkv, cosT, sinT);
  attn_split_k<<<768, 256, 0, stream>>>(qkv, g2t, g1t, lng, lnb, pO, pML, attn);
  attn_combine_k<<<256, 256, 0, stream>>>(pO, pML, g1t, lng, lnb, attn);
  // out = attn @ Wo  (4096 x 2048), fp32
  gemm_out_k<<<dim3(16, 32), 256, 0, stream>>>(attn, WoT, (float*)d_out, 4096, 2048, 2048);
}